// Round 10
// baseline (125.504 us; speedup 1.0000x reference)
//
#include <hip/hip_runtime.h>
#include <hip/hip_bf16.h>

#define DB 8
#define DT 2048
#define DC 1024
#define DH 128

typedef __attribute__((ext_vector_type(8))) short short8;
typedef __attribute__((ext_vector_type(4))) float f32x4;
typedef __attribute__((ext_vector_type(4))) int i32x4;
typedef __attribute__((ext_vector_type(4))) unsigned short u16x4;

// round-to-nearest-even f32 -> bf16 bits
static __device__ __forceinline__ unsigned short bfbits(float x){
    union { float f; unsigned u; } a; a.f = x;
    unsigned u = a.u;
    unsigned r = u + 0x7fffu + ((u >> 16) & 1u);
    return (unsigned short)(r >> 16);
}
static __device__ __forceinline__ unsigned pbf2(float lo, float hi){
    return (unsigned)bfbits(lo) | ((unsigned)bfbits(hi) << 16);
}
static __device__ __forceinline__ float bf2f(unsigned short u){
    union { unsigned u; float f; } t; t.u = ((unsigned)u) << 16; return t.f;
}

// Redistribute 32 kv-wide P slice (S^T D-layout words pk0..pk3) into the
// PV B-fragment layout (kv = 8g+i). Verified R0..R9.
static __device__ __forceinline__ short8 redist(unsigned pk0, unsigned pk1,
                                                unsigned pk2, unsigned pk3,
                                                int g, int c){
    const int src0 = c + (((2*g    ) & 3) << 4);
    const int src1 = c + (((2*g + 1) & 3) << 4);
    const int sel  = g >> 1;
    unsigned a0 = __shfl(pk0, src0), a2 = __shfl(pk2, src0);
    unsigned b0 = __shfl(pk1, src0), b2 = __shfl(pk3, src0);
    unsigned c0 = __shfl(pk0, src1), c2 = __shfl(pk2, src1);
    unsigned d0 = __shfl(pk1, src1), d2 = __shfl(pk3, src1);
    i32x4 pw = { (int)(sel ? a2 : a0), (int)(sel ? b2 : b0),
                 (int)(sel ? c2 : c0), (int)(sel ? d2 : d0) };
    return __builtin_bit_cast(short8, pw);
}

// WTc[t][chunk][n][e] = W_p[k][h] bf16, k = t*32 + chunk*8 + e, n = p*128+h.
__global__ __launch_bounds__(256) void prep_wt_kernel(const float* __restrict__ Wq,
                                                      const float* __restrict__ Wk,
                                                      const float* __restrict__ Wv,
                                                      unsigned short* __restrict__ WTc){
    int gid = blockIdx.x * 256 + threadIdx.x;      // 0 .. 393215
    int e  = gid & 7;
    int F3 = gid >> 3;
    int n  = F3 % 384;
    int ct = F3 / 384;                              // t*4 + chunk, 0..127
    int k  = (ct >> 2) * 32 + (ct & 3) * 8 + e;
    int p  = n >> 7, h = n & 127;
    const float* W = (p == 0) ? Wq : (p == 1 ? Wk : Wv);
    float v = W[(size_t)k * DH + h];
    if (p == 0) v *= 0.08838834764831845f * 1.4426950408889634f;  // H^-0.5 * log2(e)
    WTc[gid] = bfbits(v);
}

// Fused QKV projection v2 (unchanged from R7..R9 passing version).
__global__ __launch_bounds__(512, 4) void qkv_kernel(const float* __restrict__ x,
                                                     const unsigned short* __restrict__ WTc,
                                                     unsigned short* __restrict__ Qb,
                                                     unsigned short* __restrict__ Kb,
                                                     unsigned short* __restrict__ VT){
    __shared__ unsigned short Bs[2][12288];   // 2 x 24KB
    __shared__ unsigned short As[2][2560];    // 2 x 5KB  (64 rows x stride 40)

    const int tid  = threadIdx.x;
    const int lane = tid & 63;
    const int w    = tid >> 6;
    const int g = lane >> 4, c = lane & 15;
    const int m0 = blockIdx.x * 64;
    const int n0 = w * 48;

    const unsigned short* bsrc = WTc + (size_t)tid * 8;
    const bool doA = tid < 256;
    const int arow = tid >> 2, ac8 = tid & 3;
    const float* asrc = x + (size_t)(m0 + arow) * DC + ac8 * 8;

    f32x4 acc[4][3] = {};
    i32x4 breg[3];
    float4 av0, av1;

#pragma unroll
    for (int j = 0; j < 3; ++j)
        breg[j] = *(const i32x4*)(bsrc + j * 4096);
    if (doA){ av0 = *(const float4*)asrc; av1 = *(const float4*)(asrc + 4); }
#pragma unroll
    for (int j = 0; j < 3; ++j)
        *(i32x4*)(&Bs[0][j * 4096 + tid * 8]) = breg[j];
    if (doA){
        i32x4 h8 = { (int)pbf2(av0.x, av0.y), (int)pbf2(av0.z, av0.w),
                     (int)pbf2(av1.x, av1.y), (int)pbf2(av1.z, av1.w) };
        *(i32x4*)(&As[0][arow * 40 + ac8 * 8]) = h8;
    }

    for (int t = 0; t < DC / 32; ++t){
        const int cur = t & 1;
        __syncthreads();
        if (t < DC / 32 - 1){
#pragma unroll
            for (int j = 0; j < 3; ++j)
                breg[j] = *(const i32x4*)(bsrc + (t + 1) * 12288 + j * 4096);
            if (doA){
                av0 = *(const float4*)(asrc + (t + 1) * 32);
                av1 = *(const float4*)(asrc + (t + 1) * 32 + 4);
            }
        }
        short8 af[4], bfr[3];
#pragma unroll
        for (int mf = 0; mf < 4; ++mf)
            af[mf] = *(const short8*)(&As[cur][(mf*16 + c) * 40 + g * 8]);
#pragma unroll
        for (int nf = 0; nf < 3; ++nf)
            bfr[nf] = *(const short8*)(&Bs[cur][g * 3072 + (n0 + nf*16 + c) * 8]);
#pragma unroll
        for (int mf = 0; mf < 4; ++mf)
#pragma unroll
            for (int nf = 0; nf < 3; ++nf)
                acc[mf][nf] = __builtin_amdgcn_mfma_f32_16x16x32_bf16(af[mf], bfr[nf], acc[mf][nf], 0, 0, 0);
        if (t < DC / 32 - 1){
#pragma unroll
            for (int j = 0; j < 3; ++j)
                *(i32x4*)(&Bs[cur ^ 1][j * 4096 + tid * 8]) = breg[j];
            if (doA){
                i32x4 h8 = { (int)pbf2(av0.x, av0.y), (int)pbf2(av0.z, av0.w),
                             (int)pbf2(av1.x, av1.y), (int)pbf2(av1.z, av1.w) };
                *(i32x4*)(&As[cur ^ 1][arow * 40 + ac8 * 8]) = h8;
            }
        }
    }

    const int bb = m0 >> 11;
    const int tb = m0 & 2047;
#pragma unroll
    for (int mf = 0; mf < 4; ++mf)
#pragma unroll
        for (int nf = 0; nf < 3; ++nf){
            const int n  = n0 + nf*16;
            const int p  = n >> 7;
            const int np = (n & 127) + c;
            const int row = m0 + mf*16 + 4*g;
            if (p < 2){
                unsigned short* O = (p == 0) ? Qb : Kb;   // [B*T][H]
#pragma unroll
                for (int r = 0; r < 4; ++r)
                    O[(size_t)(row + r) * DH + np] = bfbits(acc[mf][nf][r]);
            } else {
                const int t0 = tb + mf*16 + 4*g;
                u16x4 v = { bfbits(acc[mf][nf][0]), bfbits(acc[mf][nf][1]),
                            bfbits(acc[mf][nf][2]), bfbits(acc[mf][nf][3]) };
                *(u16x4*)(VT + ((size_t)bb * DH + np) * DT + t0) = v;
            }
        }
}

// Causal flash attention v5: kv-split-4, 1 wave/block, no LDS, no barriers.
// Grid 4096: block = (batch bi&7, 16-row q-tile, split s); wave handles
// kv-tiles kt = s, s+4, ... -> 16 waves/CU of TLP. Partial O (bf16) + (m,l)
// written to ws; merge_kernel combines the 4 splits.
__global__ __launch_bounds__(64) void attn_kernel(const unsigned short* __restrict__ Qb,
                                                  const unsigned short* __restrict__ Kb,
                                                  const unsigned short* __restrict__ VT,
                                                  unsigned short* __restrict__ OP,
                                                  float* __restrict__ ML){
    const int lane = threadIdx.x;
    const int g = lane >> 4, c = lane & 15;
    const int bi = blockIdx.x;
    const int b  = bi & 7;                 // batch == XCD (bi % 8)
    const int idx = bi >> 3;               // 0..511
    const int qt = idx & 127;
    const int split = idx >> 7;            // 0..3
    const int q0 = qt * 16;
    const int q  = q0 + c;
    const int nt = (qt >> 2) + 1;          // kv-iterations of 64

    const unsigned short* Kbase = Kb + (size_t)b * DT * DH;
    const unsigned short* Vbase = VT + (size_t)b * DH * DT;

    short8 qf[4];
#pragma unroll
    for (int hc = 0; hc < 4; ++hc)
        qf[hc] = *(const short8*)(Qb + ((size_t)b*DT + q0 + c) * DH + hc*32 + g*8);

    f32x4 acc[8] = {};
    float m = -1e30f, l = 0.f;

    for (int kt = split; kt < nt; kt += 4){
        const int kv0 = kt * 64;

        // ---- K fragments + QK^T ----
        short8 kf[4][4];
#pragma unroll
        for (int j = 0; j < 4; ++j)
#pragma unroll
            for (int hc = 0; hc < 4; ++hc)
                kf[j][hc] = *(const short8*)(Kbase + (size_t)(kv0 + 16*j + c) * DH + hc*32 + g*8);

        f32x4 s4[4] = {};
        __builtin_amdgcn_s_setprio(1);
#pragma unroll
        for (int hc = 0; hc < 4; ++hc)
#pragma unroll
            for (int j = 0; j < 4; ++j)
                s4[j] = __builtin_amdgcn_mfma_f32_16x16x32_bf16(kf[j][hc], qf[hc], s4[j], 0,0,0);
        __builtin_amdgcn_s_setprio(0);

        // ---- V fragments issued during softmax ----
        short8 vf0[8], vf1[8];
#pragma unroll
        for (int mt = 0; mt < 8; ++mt){
            const unsigned short* vp = Vbase + (size_t)(mt*16 + c) * DT + kv0 + g*8;
            vf0[mt] = *(const short8*)vp;
            vf1[mt] = *(const short8*)(vp + 32);
        }

        // ---- causal mask (globally-last tile only) ----
        if (kt == nt - 1){
#pragma unroll
            for (int j = 0; j < 4; ++j){
                const int o = kv0 + 16*j + 4*g;
#pragma unroll
                for (int r = 0; r < 4; ++r)
                    if (o + r > q) s4[j][r] = -1e30f;
            }
        }

        // ---- online softmax with defer-max (T13) ----
        float tm = -1e30f;
#pragma unroll
        for (int j = 0; j < 4; ++j)
#pragma unroll
            for (int r = 0; r < 4; ++r) tm = fmaxf(tm, s4[j][r]);
        tm = fmaxf(tm, __shfl_xor(tm, 16));
        tm = fmaxf(tm, __shfl_xor(tm, 32));
        if (!__all(tm <= m + 8.f)){
            const float mn = fmaxf(m, tm);
            const float rs = exp2f(m - mn);
            l *= rs;
#pragma unroll
            for (int mt = 0; mt < 8; ++mt) acc[mt] *= rs;
            m = mn;
        }
        float p[4][4]; float ps = 0.f;
#pragma unroll
        for (int j = 0; j < 4; ++j)
#pragma unroll
            for (int r = 0; r < 4; ++r){
                p[j][r] = exp2f(s4[j][r] - m);
                ps += p[j][r];
            }
        ps += __shfl_xor(ps, 16);
        ps += __shfl_xor(ps, 32);
        l += ps;

        // ---- P -> B-fragment layout, two 32-wide halves ----
        short8 pf0 = redist(pbf2(p[0][0], p[0][1]), pbf2(p[0][2], p[0][3]),
                            pbf2(p[1][0], p[1][1]), pbf2(p[1][2], p[1][3]), g, c);
        short8 pf1 = redist(pbf2(p[2][0], p[2][1]), pbf2(p[2][2], p[2][3]),
                            pbf2(p[3][0], p[3][1]), pbf2(p[3][2], p[3][3]), g, c);

        // ---- PV ----
        __builtin_amdgcn_s_setprio(1);
#pragma unroll
        for (int mt = 0; mt < 8; ++mt){
            acc[mt] = __builtin_amdgcn_mfma_f32_16x16x32_bf16(vf0[mt], pf0, acc[mt], 0,0,0);
            acc[mt] = __builtin_amdgcn_mfma_f32_16x16x32_bf16(vf1[mt], pf1, acc[mt], 0,0,0);
        }
        __builtin_amdgcn_s_setprio(0);
    }

    // ---- store partial (bf16 O, f32 m/l) ----
    const size_t tb4 = (size_t)(b * 128 + qt) * 4 + split;
    unsigned short* op = OP + tb4 * 2048;
#pragma unroll
    for (int mt = 0; mt < 8; ++mt){
        u16x4 h = { bfbits(acc[mt][0]), bfbits(acc[mt][1]),
                    bfbits(acc[mt][2]), bfbits(acc[mt][3]) };
        *(u16x4*)(op + c*128 + mt*16 + 4*g) = h;
    }
    if (g == 0){
        ML[(tb4*16 + c)*2    ] = m;
        ML[(tb4*16 + c)*2 + 1] = l;
    }
}

// Combine the 4 kv-split partials per q-tile. Grid 1024 x 64 (b = bi&7).
__global__ __launch_bounds__(64) void merge_kernel(const unsigned short* __restrict__ OP,
                                                   const float* __restrict__ ML,
                                                   float* __restrict__ out){
    const int lane = threadIdx.x;
    const int r  = lane >> 2;              // row 0..15
    const int cq = (lane & 3) * 32;        // col base
    const int bi = blockIdx.x;
    const int b  = bi & 7;
    const int qt = bi >> 3;
    const size_t tb4 = (size_t)(b * 128 + qt) * 4;

    float ms[4], ls[4];
#pragma unroll
    for (int s = 0; s < 4; ++s){
        ms[s] = ML[((tb4 + s)*16 + r)*2    ];
        ls[s] = ML[((tb4 + s)*16 + r)*2 + 1];
    }
    float M = fmaxf(fmaxf(ms[0], ms[1]), fmaxf(ms[2], ms[3]));
    float sc[4]; float L = 0.f;
#pragma unroll
    for (int s = 0; s < 4; ++s){ sc[s] = exp2f(ms[s] - M); L += ls[s] * sc[s]; }
    const float inv = 1.0f / L;

    float* orow = out + ((size_t)(b * DT + qt*16 + r)) * DH + cq;
#pragma unroll
    for (int j = 0; j < 4; ++j){
        float o[8] = {};
#pragma unroll
        for (int s = 0; s < 4; ++s){
            short8 v = *(const short8*)(OP + (tb4 + s)*2048 + r*128 + cq + j*8);
#pragma unroll
            for (int e = 0; e < 8; ++e)
                o[e] += bf2f((unsigned short)v[e]) * sc[s];
        }
        f32x4 o0 = { o[0]*inv, o[1]*inv, o[2]*inv, o[3]*inv };
        f32x4 o1 = { o[4]*inv, o[5]*inv, o[6]*inv, o[7]*inv };
        *(f32x4*)(orow + j*8    ) = o0;
        *(f32x4*)(orow + j*8 + 4) = o1;
    }
}

extern "C" void kernel_launch(void* const* d_in, const int* in_sizes, int n_in,
                              void* d_out, int out_size, void* d_ws, size_t ws_size,
                              hipStream_t stream){
    const float* x  = (const float*)d_in[0];
    const float* Wq = (const float*)d_in[1];
    const float* Wk = (const float*)d_in[2];
    const float* Wv = (const float*)d_in[3];
    float* out = (float*)d_out;

    unsigned short* WTc = (unsigned short*)d_ws;         // [32][4][384][8] bf16
    unsigned short* Qb = WTc + 3 * DH * DC;              // [B*T][H]
    unsigned short* Kb = Qb + (size_t)DB * DT * DH;      // [B*T][H]
    unsigned short* VT = Kb + (size_t)DB * DT * DH;      // [B][H][T]
    unsigned short* OP = VT + (size_t)DB * DT * DH;      // [1024][4][16][128] bf16
    float*          ML = (float*)(OP + (size_t)1024 * 4 * 2048);  // [1024][4][16][2] f32

    hipLaunchKernelGGL(prep_wt_kernel, dim3(1536), dim3(256), 0, stream, Wq, Wk, Wv, WTc);
    hipLaunchKernelGGL(qkv_kernel, dim3(256), dim3(512), 0, stream, x, WTc, Qb, Kb, VT);
    hipLaunchKernelGGL(attn_kernel, dim3(4096), dim3(64), 0, stream, Qb, Kb, VT, OP, ML);
    hipLaunchKernelGGL(merge_kernel, dim3(1024), dim3(64), 0, stream, OP, ML, out);
}

// Round 11
// 81.112 us; speedup vs baseline: 1.5473x; 1.5473x over previous
//
#include <hip/hip_runtime.h>
#include <hip/hip_bf16.h>

#define DB 8
#define DT 2048
#define DC 1024
#define DH 128

typedef __attribute__((ext_vector_type(8))) short short8;
typedef __attribute__((ext_vector_type(4))) float f32x4;
typedef __attribute__((ext_vector_type(4))) int i32x4;
typedef __attribute__((ext_vector_type(4))) unsigned short u16x4;

// round-to-nearest-even f32 -> bf16 bits
static __device__ __forceinline__ unsigned short bfbits(float x){
    union { float f; unsigned u; } a; a.f = x;
    unsigned u = a.u;
    unsigned r = u + 0x7fffu + ((u >> 16) & 1u);
    return (unsigned short)(r >> 16);
}
static __device__ __forceinline__ unsigned pbf2(float lo, float hi){
    return (unsigned)bfbits(lo) | ((unsigned)bfbits(hi) << 16);
}
static __device__ __forceinline__ float bf2f(unsigned short u){
    union { unsigned u; float f; } t; t.u = ((unsigned)u) << 16; return t.f;
}

// Redistribute 32 kv-wide P slice into PV B-fragment layout. Verified R0..R10.
static __device__ __forceinline__ short8 redist(unsigned pk0, unsigned pk1,
                                                unsigned pk2, unsigned pk3,
                                                int g, int c){
    const int src0 = c + (((2*g    ) & 3) << 4);
    const int src1 = c + (((2*g + 1) & 3) << 4);
    const int sel  = g >> 1;
    unsigned a0 = __shfl(pk0, src0), a2 = __shfl(pk2, src0);
    unsigned b0 = __shfl(pk1, src0), b2 = __shfl(pk3, src0);
    unsigned c0 = __shfl(pk0, src1), c2 = __shfl(pk2, src1);
    unsigned d0 = __shfl(pk1, src1), d2 = __shfl(pk3, src1);
    i32x4 pw = { (int)(sel ? a2 : a0), (int)(sel ? b2 : b0),
                 (int)(sel ? c2 : c0), (int)(sel ? d2 : d0) };
    return __builtin_bit_cast(short8, pw);
}

// WTc[t][chunk][n][e] = W_p[k][h] bf16 (unchanged).
__global__ __launch_bounds__(256) void prep_wt_kernel(const float* __restrict__ Wq,
                                                      const float* __restrict__ Wk,
                                                      const float* __restrict__ Wv,
                                                      unsigned short* __restrict__ WTc){
    int gid = blockIdx.x * 256 + threadIdx.x;
    int e  = gid & 7;
    int F3 = gid >> 3;
    int n  = F3 % 384;
    int ct = F3 / 384;
    int k  = (ct >> 2) * 32 + (ct & 3) * 8 + e;
    int p  = n >> 7, h = n & 127;
    const float* W = (p == 0) ? Wq : (p == 1 ? Wk : Wv);
    float v = W[(size_t)k * DH + h];
    if (p == 0) v *= 0.08838834764831845f * 1.4426950408889634f;
    WTc[gid] = bfbits(v);
}

// Fused QKV projection v2 (unchanged from R7..R10 passing version).
__global__ __launch_bounds__(512, 4) void qkv_kernel(const float* __restrict__ x,
                                                     const unsigned short* __restrict__ WTc,
                                                     unsigned short* __restrict__ Qb,
                                                     unsigned short* __restrict__ Kb,
                                                     unsigned short* __restrict__ VT){
    __shared__ unsigned short Bs[2][12288];
    __shared__ unsigned short As[2][2560];

    const int tid  = threadIdx.x;
    const int lane = tid & 63;
    const int w    = tid >> 6;
    const int g = lane >> 4, c = lane & 15;
    const int m0 = blockIdx.x * 64;
    const int n0 = w * 48;

    const unsigned short* bsrc = WTc + (size_t)tid * 8;
    const bool doA = tid < 256;
    const int arow = tid >> 2, ac8 = tid & 3;
    const float* asrc = x + (size_t)(m0 + arow) * DC + ac8 * 8;

    f32x4 acc[4][3] = {};
    i32x4 breg[3];
    float4 av0, av1;

#pragma unroll
    for (int j = 0; j < 3; ++j)
        breg[j] = *(const i32x4*)(bsrc + j * 4096);
    if (doA){ av0 = *(const float4*)asrc; av1 = *(const float4*)(asrc + 4); }
#pragma unroll
    for (int j = 0; j < 3; ++j)
        *(i32x4*)(&Bs[0][j * 4096 + tid * 8]) = breg[j];
    if (doA){
        i32x4 h8 = { (int)pbf2(av0.x, av0.y), (int)pbf2(av0.z, av0.w),
                     (int)pbf2(av1.x, av1.y), (int)pbf2(av1.z, av1.w) };
        *(i32x4*)(&As[0][arow * 40 + ac8 * 8]) = h8;
    }

    for (int t = 0; t < DC / 32; ++t){
        const int cur = t & 1;
        __syncthreads();
        if (t < DC / 32 - 1){
#pragma unroll
            for (int j = 0; j < 3; ++j)
                breg[j] = *(const i32x4*)(bsrc + (t + 1) * 12288 + j * 4096);
            if (doA){
                av0 = *(const float4*)(asrc + (t + 1) * 32);
                av1 = *(const float4*)(asrc + (t + 1) * 32 + 4);
            }
        }
        short8 af[4], bfr[3];
#pragma unroll
        for (int mf = 0; mf < 4; ++mf)
            af[mf] = *(const short8*)(&As[cur][(mf*16 + c) * 40 + g * 8]);
#pragma unroll
        for (int nf = 0; nf < 3; ++nf)
            bfr[nf] = *(const short8*)(&Bs[cur][g * 3072 + (n0 + nf*16 + c) * 8]);
#pragma unroll
        for (int mf = 0; mf < 4; ++mf)
#pragma unroll
            for (int nf = 0; nf < 3; ++nf)
                acc[mf][nf] = __builtin_amdgcn_mfma_f32_16x16x32_bf16(af[mf], bfr[nf], acc[mf][nf], 0, 0, 0);
        if (t < DC / 32 - 1){
#pragma unroll
            for (int j = 0; j < 3; ++j)
                *(i32x4*)(&Bs[cur ^ 1][j * 4096 + tid * 8]) = breg[j];
            if (doA){
                i32x4 h8 = { (int)pbf2(av0.x, av0.y), (int)pbf2(av0.z, av0.w),
                             (int)pbf2(av1.x, av1.y), (int)pbf2(av1.z, av1.w) };
                *(i32x4*)(&As[cur ^ 1][arow * 40 + ac8 * 8]) = h8;
            }
        }
    }

    const int bb = m0 >> 11;
    const int tb = m0 & 2047;
#pragma unroll
    for (int mf = 0; mf < 4; ++mf)
#pragma unroll
        for (int nf = 0; nf < 3; ++nf){
            const int n  = n0 + nf*16;
            const int p  = n >> 7;
            const int np = (n & 127) + c;
            const int row = m0 + mf*16 + 4*g;
            if (p < 2){
                unsigned short* O = (p == 0) ? Qb : Kb;
#pragma unroll
                for (int r = 0; r < 4; ++r)
                    O[(size_t)(row + r) * DH + np] = bfbits(acc[mf][nf][r]);
            } else {
                const int t0 = tb + mf*16 + 4*g;
                u16x4 v = { bfbits(acc[mf][nf][0]), bfbits(acc[mf][nf][1]),
                            bfbits(acc[mf][nf][2]), bfbits(acc[mf][nf][3]) };
                *(u16x4*)(VT + ((size_t)bb * DH + np) * DT + t0) = v;
            }
        }
}

// Causal flash attention v6: R6's 4-wave shared-LDS block, kv-split-2 so two
// blocks fit per CU (32KB single buffer, two-barrier reg-prefetch loop).
// Grid 512: b = bi&7 (XCD pin); idx = bi>>3: qt = idx<32 ? 31-idx : idx-32,
// half = idx>>5 (complementary big+small pairing per CU). Partials (bf16 O,
// f32 m/l) merged by merge_kernel.
__global__ __launch_bounds__(256, 2) void attn_kernel(const unsigned short* __restrict__ Qb,
                                                      const unsigned short* __restrict__ Kb,
                                                      const unsigned short* __restrict__ VT,
                                                      unsigned short* __restrict__ OP,
                                                      float* __restrict__ ML){
    __shared__ unsigned char lds[32768];   // K 16KB @0, V 16KB @16384

    const int tid  = threadIdx.x;
    const int lane = tid & 63;
    const int w    = tid >> 6;
    const int g = lane >> 4, c = lane & 15;
    const int bi = blockIdx.x;
    const int b  = bi & 7;
    const int idx = bi >> 3;               // 0..63
    const int qt   = (idx < 32) ? (31 - idx) : (idx - 32);
    const int half = idx >> 5;
    const int q0 = qt * 64;
    const int qw = q0 + 16 * w;
    const int q  = qw + c;
    const int nt = qt + 1;                 // total kv tiles for this q-tile
    const int h1 = (nt + 1) >> 1;          // split point
    const int kt0 = half ? h1 : 0;
    const int kt1 = half ? nt : h1;

    const unsigned short* Kbase = Kb + (size_t)b * DT * DH;
    const unsigned short* Vbase = VT + (size_t)b * DH * DT;

    short8 qf[4];
#pragma unroll
    for (int hc = 0; hc < 4; ++hc)
        qf[hc] = *(const short8*)(Qb + ((size_t)b*DT + qw + c) * DH + hc*32 + g*8);

    f32x4 acc[8] = {};
    float m = -1e30f, l = 0.f;

    i32x4 kreg[4], vreg[4];
    if (kt0 < kt1){
        const int kv0 = kt0 * 64;
        // ---- prologue: stage first tile ----
#pragma unroll
        for (int p = 0; p < 4; ++p){
            const int s = p*256 + tid;
            kreg[p] = *(const i32x4*)(Kbase + (size_t)(kv0 + (s >> 4)) * DH + (s & 15) * 8);
            vreg[p] = *(const i32x4*)(Vbase + (size_t)(s >> 3) * DT + kv0 + (s & 7) * 8);
        }
#pragma unroll
        for (int p = 0; p < 4; ++p){
            const int s = p*256 + tid;
            const int r = s >> 4, cb = (s & 15) * 16;
            *(i32x4*)(lds + r*256 + (cb ^ ((r & 7) << 4))) = kreg[p];
            const int h = s >> 3, tb = (s & 7) * 16;
            *(i32x4*)(lds + 16384 + h*128 + (tb ^ ((h & 7) << 4))) = vreg[p];
        }

        for (int kt = kt0; kt < kt1; ++kt){
            const int kv0c = kt * 64;
            __syncthreads();                      // staged tile visible

            // ---- issue next tile's global loads early (T14) ----
            if (kt + 1 < kt1){
                const int nv0 = kv0c + 64;
#pragma unroll
                for (int p = 0; p < 4; ++p){
                    const int s = p*256 + tid;
                    kreg[p] = *(const i32x4*)(Kbase + (size_t)(nv0 + (s >> 4)) * DH + (s & 15) * 8);
                    vreg[p] = *(const i32x4*)(Vbase + (size_t)(s >> 3) * DT + nv0 + (s & 7) * 8);
                }
            }

            // ---- QK^T from LDS K ----
            f32x4 s4[4] = {};
            short8 kf[4][4];
#pragma unroll
            for (int j = 0; j < 4; ++j){
                const int r = 16*j + c;
#pragma unroll
                for (int hc = 0; hc < 4; ++hc)
                    kf[j][hc] = *(const short8*)(lds + r*256 + ((hc*64 + g*16) ^ ((r & 7) << 4)));
            }
            __builtin_amdgcn_s_setprio(1);
#pragma unroll
            for (int hc = 0; hc < 4; ++hc)
#pragma unroll
                for (int j = 0; j < 4; ++j)
                    s4[j] = __builtin_amdgcn_mfma_f32_16x16x32_bf16(kf[j][hc], qf[hc], s4[j], 0,0,0);
            __builtin_amdgcn_s_setprio(0);

            // ---- causal mask (diagonal tile only) ----
            if (kt == nt - 1){
#pragma unroll
                for (int j = 0; j < 4; ++j){
                    const int o = kv0c + 16*j + 4*g;
#pragma unroll
                    for (int r = 0; r < 4; ++r)
                        if (o + r > q) s4[j][r] = -1e30f;
                }
            }

            // ---- online softmax with defer-max (T13) ----
            float tm = -1e30f;
#pragma unroll
            for (int j = 0; j < 4; ++j)
#pragma unroll
                for (int r = 0; r < 4; ++r) tm = fmaxf(tm, s4[j][r]);
            tm = fmaxf(tm, __shfl_xor(tm, 16));
            tm = fmaxf(tm, __shfl_xor(tm, 32));
            if (!__all(tm <= m + 8.f)){
                const float mn = fmaxf(m, tm);
                const float rs = exp2f(m - mn);
                l *= rs;
#pragma unroll
                for (int mt = 0; mt < 8; ++mt) acc[mt] *= rs;
                m = mn;
            }
            float p[4][4]; float ps = 0.f;
#pragma unroll
            for (int j = 0; j < 4; ++j)
#pragma unroll
                for (int r = 0; r < 4; ++r){
                    p[j][r] = exp2f(s4[j][r] - m);
                    ps += p[j][r];
                }
            ps += __shfl_xor(ps, 16);
            ps += __shfl_xor(ps, 32);
            l += ps;

            // ---- P -> B-fragment layout ----
            short8 pf0 = redist(pbf2(p[0][0], p[0][1]), pbf2(p[0][2], p[0][3]),
                                pbf2(p[1][0], p[1][1]), pbf2(p[1][2], p[1][3]), g, c);
            short8 pf1 = redist(pbf2(p[2][0], p[2][1]), pbf2(p[2][2], p[2][3]),
                                pbf2(p[3][0], p[3][1]), pbf2(p[3][2], p[3][3]), g, c);

            // ---- PV from LDS V ----
#pragma unroll
            for (int kk = 0; kk < 2; ++kk){
                short8 vf[8];
#pragma unroll
                for (int mt = 0; mt < 8; ++mt){
                    const int h = mt*16 + c;
                    vf[mt] = *(const short8*)(lds + 16384 + h*128 + ((kk*64 + g*16) ^ ((h & 7) << 4)));
                }
                const short8 pf = kk ? pf1 : pf0;
                __builtin_amdgcn_s_setprio(1);
#pragma unroll
                for (int mt = 0; mt < 8; ++mt)
                    acc[mt] = __builtin_amdgcn_mfma_f32_16x16x32_bf16(vf[mt], pf, acc[mt], 0,0,0);
                __builtin_amdgcn_s_setprio(0);
            }

            __syncthreads();                      // all reads of lds done
            // ---- write next tile (late, T14) ----
            if (kt + 1 < kt1){
#pragma unroll
                for (int p2 = 0; p2 < 4; ++p2){
                    const int s = p2*256 + tid;
                    const int r = s >> 4, cb = (s & 15) * 16;
                    *(i32x4*)(lds + r*256 + (cb ^ ((r & 7) << 4))) = kreg[p2];
                    const int h = s >> 3, tb = (s & 7) * 16;
                    *(i32x4*)(lds + 16384 + h*128 + (tb ^ ((h & 7) << 4))) = vreg[p2];
                }
            }
        }
    }

    // ---- store partial (bf16 O, f32 m/l) ----
    const size_t blk = ((size_t)(b * 32 + qt) * 2 + half);
    unsigned short* op = OP + blk * 8192;          // [64][128]
    const int row = 16*w + c;
#pragma unroll
    for (int mt = 0; mt < 8; ++mt){
        u16x4 h = { bfbits(acc[mt][0]), bfbits(acc[mt][1]),
                    bfbits(acc[mt][2]), bfbits(acc[mt][3]) };
        *(u16x4*)(op + row*128 + mt*16 + 4*g) = h;
    }
    if (g == 0){
        ML[(blk*64 + row)*2    ] = m;
        ML[(blk*64 + row)*2 + 1] = l;
    }
}

// 2-way merge. Grid 256 = (b, qt), 256 threads: r = tid>>2, colgroup = tid&3.
__global__ __launch_bounds__(256) void merge_kernel(const unsigned short* __restrict__ OP,
                                                    const float* __restrict__ ML,
                                                    float* __restrict__ out){
    const int tid = threadIdx.x;
    const int r  = tid >> 2;
    const int cq = (tid & 3) * 32;
    const int bi = blockIdx.x;
    const int b  = bi & 7;
    const int qt = bi >> 3;
    const size_t blk = (size_t)(b * 32 + qt) * 2;

    float ms[2], ls[2];
#pragma unroll
    for (int s = 0; s < 2; ++s){
        ms[s] = ML[((blk + s)*64 + r)*2    ];
        ls[s] = ML[((blk + s)*64 + r)*2 + 1];
    }
    const float M = fmaxf(ms[0], ms[1]);
    float sc[2]; float L = 0.f;
#pragma unroll
    for (int s = 0; s < 2; ++s){ sc[s] = exp2f(ms[s] - M); L += ls[s] * sc[s]; }
    const float inv = 1.0f / L;

    float* orow = out + ((size_t)(b * DT + qt*64 + r)) * DH + cq;
#pragma unroll
    for (int j = 0; j < 4; ++j){
        float o[8] = {};
#pragma unroll
        for (int s = 0; s < 2; ++s){
            short8 v = *(const short8*)(OP + (blk + s)*8192 + r*128 + cq + j*8);
#pragma unroll
            for (int e = 0; e < 8; ++e)
                o[e] += bf2f((unsigned short)v[e]) * sc[s];
        }
        f32x4 o0 = { o[0]*inv, o[1]*inv, o[2]*inv, o[3]*inv };
        f32x4 o1 = { o[4]*inv, o[5]*inv, o[6]*inv, o[7]*inv };
        *(f32x4*)(orow + j*8    ) = o0;
        *(f32x4*)(orow + j*8 + 4) = o1;
    }
}

extern "C" void kernel_launch(void* const* d_in, const int* in_sizes, int n_in,
                              void* d_out, int out_size, void* d_ws, size_t ws_size,
                              hipStream_t stream){
    const float* x  = (const float*)d_in[0];
    const float* Wq = (const float*)d_in[1];
    const float* Wk = (const float*)d_in[2];
    const float* Wv = (const float*)d_in[3];
    float* out = (float*)d_out;

    unsigned short* WTc = (unsigned short*)d_ws;         // [32][4][384][8] bf16
    unsigned short* Qb = WTc + 3 * DH * DC;              // [B*T][H]
    unsigned short* Kb = Qb + (size_t)DB * DT * DH;      // [B*T][H]
    unsigned short* VT = Kb + (size_t)DB * DT * DH;      // [B][H][T]
    unsigned short* OP = VT + (size_t)DB * DT * DH;      // [512][64][128] bf16
    float*          ML = (float*)(OP + (size_t)512 * 8192);  // [512][64][2] f32

    hipLaunchKernelGGL(prep_wt_kernel, dim3(1536), dim3(256), 0, stream, Wq, Wk, Wv, WTc);
    hipLaunchKernelGGL(qkv_kernel, dim3(256), dim3(512), 0, stream, x, WTc, Qb, Kb, VT);
    hipLaunchKernelGGL(attn_kernel, dim3(512), dim3(256), 0, stream, Qb, Kb, VT, OP, ML);
    hipLaunchKernelGGL(merge_kernel, dim3(256), dim3(256), 0, stream, OP, ML, out);
}

// Round 12
// 78.267 us; speedup vs baseline: 1.6035x; 1.0363x over previous
//
#include <hip/hip_runtime.h>
#include <hip/hip_bf16.h>

#define DB 8
#define DT 2048
#define DC 1024
#define DH 128

typedef __attribute__((ext_vector_type(8))) short short8;
typedef __attribute__((ext_vector_type(4))) float f32x4;
typedef __attribute__((ext_vector_type(4))) int i32x4;
typedef __attribute__((ext_vector_type(4))) unsigned short u16x4;

// round-to-nearest-even f32 -> bf16 bits
static __device__ __forceinline__ unsigned short bfbits(float x){
    union { float f; unsigned u; } a; a.f = x;
    unsigned u = a.u;
    unsigned r = u + 0x7fffu + ((u >> 16) & 1u);
    return (unsigned short)(r >> 16);
}
static __device__ __forceinline__ unsigned pbf2(float lo, float hi){
    return (unsigned)bfbits(lo) | ((unsigned)bfbits(hi) << 16);
}
static __device__ __forceinline__ float bf2f(unsigned short u){
    union { unsigned u; float f; } t; t.u = ((unsigned)u) << 16; return t.f;
}

// async 16B global -> LDS (direct, no VGPR round-trip)
static __device__ __forceinline__ void gload16(const void* g, void* l){
    __builtin_amdgcn_global_load_lds(
        (const __attribute__((address_space(1))) unsigned int*)g,
        (__attribute__((address_space(3))) unsigned int*)l, 16, 0, 0);
}

// Redistribute 32 kv-wide P slice into PV B-fragment layout. Verified R0..R11.
static __device__ __forceinline__ short8 redist(unsigned pk0, unsigned pk1,
                                                unsigned pk2, unsigned pk3,
                                                int g, int c){
    const int src0 = c + (((2*g    ) & 3) << 4);
    const int src1 = c + (((2*g + 1) & 3) << 4);
    const int sel  = g >> 1;
    unsigned a0 = __shfl(pk0, src0), a2 = __shfl(pk2, src0);
    unsigned b0 = __shfl(pk1, src0), b2 = __shfl(pk3, src0);
    unsigned c0 = __shfl(pk0, src1), c2 = __shfl(pk2, src1);
    unsigned d0 = __shfl(pk1, src1), d2 = __shfl(pk3, src1);
    i32x4 pw = { (int)(sel ? a2 : a0), (int)(sel ? b2 : b0),
                 (int)(sel ? c2 : c0), (int)(sel ? d2 : d0) };
    return __builtin_bit_cast(short8, pw);
}

// WTc[t][chunk][n][e] = W_p[k][h] bf16 (unchanged).
__global__ __launch_bounds__(256) void prep_wt_kernel(const float* __restrict__ Wq,
                                                      const float* __restrict__ Wk,
                                                      const float* __restrict__ Wv,
                                                      unsigned short* __restrict__ WTc){
    int gid = blockIdx.x * 256 + threadIdx.x;
    int e  = gid & 7;
    int F3 = gid >> 3;
    int n  = F3 % 384;
    int ct = F3 / 384;
    int k  = (ct >> 2) * 32 + (ct & 3) * 8 + e;
    int p  = n >> 7, h = n & 127;
    const float* W = (p == 0) ? Wq : (p == 1 ? Wk : Wv);
    float v = W[(size_t)k * DH + h];
    if (p == 0) v *= 0.08838834764831845f * 1.4426950408889634f;
    WTc[gid] = bfbits(v);
}

// Fused QKV projection v3: B-tile staged via global_load_lds (linear dest,
// lane-linear source), A-tile reg-staged with f32->bf16 cvt. One barrier/iter.
__global__ __launch_bounds__(512, 4) void qkv_kernel(const float* __restrict__ x,
                                                     const unsigned short* __restrict__ WTc,
                                                     unsigned short* __restrict__ Qb,
                                                     unsigned short* __restrict__ Kb,
                                                     unsigned short* __restrict__ VT){
    __shared__ unsigned short Bs[2][12288];   // 2 x 24KB
    __shared__ unsigned short As[2][2560];    // 2 x 5KB  (64 rows x stride 40)

    const int tid  = threadIdx.x;
    const int lane = tid & 63;
    const int w    = tid >> 6;
    const int g = lane >> 4, c = lane & 15;
    const int m0 = blockIdx.x * 64;
    const int n0 = w * 48;

    const unsigned short* bsrc = WTc + (size_t)tid * 8;   // + j*4096 + t*12288
    const bool doA = tid < 256;
    const int arow = tid >> 2, ac8 = tid & 3;
    const float* asrc = x + (size_t)(m0 + arow) * DC + ac8 * 8;

    f32x4 acc[4][3] = {};
    float4 av0, av1;

    // ---- prologue: stage tile 0 ----
#pragma unroll
    for (int j = 0; j < 3; ++j)
        gload16(bsrc + j * 4096, &Bs[0][j * 4096 + tid * 8]);
    if (doA){
        av0 = *(const float4*)asrc; av1 = *(const float4*)(asrc + 4);
        i32x4 h8 = { (int)pbf2(av0.x, av0.y), (int)pbf2(av0.z, av0.w),
                     (int)pbf2(av1.x, av1.y), (int)pbf2(av1.z, av1.w) };
        *(i32x4*)(&As[0][arow * 40 + ac8 * 8]) = h8;
    }

    for (int t = 0; t < DC / 32; ++t){
        const int cur = t & 1;
        __syncthreads();                 // buf[cur] staged (vmcnt drained)
        if (t < DC / 32 - 1){
            // issue next B tile direct-to-LDS; A loads to regs (T14)
#pragma unroll
            for (int j = 0; j < 3; ++j)
                gload16(bsrc + (t + 1) * 12288 + j * 4096,
                        &Bs[cur ^ 1][j * 4096 + tid * 8]);
            if (doA){
                av0 = *(const float4*)(asrc + (t + 1) * 32);
                av1 = *(const float4*)(asrc + (t + 1) * 32 + 4);
            }
        }
        short8 af[4], bfr[3];
#pragma unroll
        for (int mf = 0; mf < 4; ++mf)
            af[mf] = *(const short8*)(&As[cur][(mf*16 + c) * 40 + g * 8]);
#pragma unroll
        for (int nf = 0; nf < 3; ++nf)
            bfr[nf] = *(const short8*)(&Bs[cur][g * 3072 + (n0 + nf*16 + c) * 8]);
#pragma unroll
        for (int mf = 0; mf < 4; ++mf)
#pragma unroll
            for (int nf = 0; nf < 3; ++nf)
                acc[mf][nf] = __builtin_amdgcn_mfma_f32_16x16x32_bf16(af[mf], bfr[nf], acc[mf][nf], 0, 0, 0);
        if (t < DC / 32 - 1 && doA){
            i32x4 h8 = { (int)pbf2(av0.x, av0.y), (int)pbf2(av0.z, av0.w),
                         (int)pbf2(av1.x, av1.y), (int)pbf2(av1.z, av1.w) };
            *(i32x4*)(&As[cur ^ 1][arow * 40 + ac8 * 8]) = h8;
        }
    }

    const int bb = m0 >> 11;
    const int tb = m0 & 2047;
#pragma unroll
    for (int mf = 0; mf < 4; ++mf)
#pragma unroll
        for (int nf = 0; nf < 3; ++nf){
            const int n  = n0 + nf*16;
            const int p  = n >> 7;
            const int np = (n & 127) + c;
            const int row = m0 + mf*16 + 4*g;
            if (p < 2){
                unsigned short* O = (p == 0) ? Qb : Kb;
#pragma unroll
                for (int r = 0; r < 4; ++r)
                    O[(size_t)(row + r) * DH + np] = bfbits(acc[mf][nf][r]);
            } else {
                const int t0 = tb + mf*16 + 4*g;
                u16x4 v = { bfbits(acc[mf][nf][0]), bfbits(acc[mf][nf][1]),
                            bfbits(acc[mf][nf][2]), bfbits(acc[mf][nf][3]) };
                *(u16x4*)(VT + ((size_t)bb * DH + np) * DT + t0) = v;
            }
        }
}

// Causal flash attention v7: v6 structure, but K/V staged via global_load_lds
// with pre-swizzled SOURCE (linear LDS dest; reads keep their XOR swizzle) and
// double-buffered 2x32KB -> ONE barrier per kv-iteration, no write-back phase.
__global__ __launch_bounds__(256, 2) void attn_kernel(const unsigned short* __restrict__ Qb,
                                                      const unsigned short* __restrict__ Kb,
                                                      const unsigned short* __restrict__ VT,
                                                      unsigned short* __restrict__ OP,
                                                      float* __restrict__ ML){
    __shared__ unsigned char lds[2][32768];   // per buf: K 16KB @0, V 16KB @16384

    const int tid  = threadIdx.x;
    const int lane = tid & 63;
    const int w    = tid >> 6;
    const int g = lane >> 4, c = lane & 15;
    const int bi = blockIdx.x;
    const int b  = bi & 7;
    const int idx = bi >> 3;               // 0..63
    const int qt   = (idx < 32) ? (31 - idx) : (idx - 32);
    const int half = idx >> 5;
    const int q0 = qt * 64;
    const int qw = q0 + 16 * w;
    const int q  = qw + c;
    const int nt = qt + 1;
    const int h1 = (nt + 1) >> 1;
    const int kt0 = half ? h1 : 0;
    const int kt1 = half ? nt : h1;

    const unsigned short* Kbase = Kb + (size_t)b * DT * DH;
    const unsigned short* Vbase = VT + (size_t)b * DH * DT;

    // staging maps (s = p*256 + tid): K dest slot s*16 holds source column
    // (cbl ^ ((r&7)<<4)) of K row r; reads then apply the same XOR.
    const int sK_r[4]  = { (0*256 + tid) >> 4, (1*256 + tid) >> 4,
                           (2*256 + tid) >> 4, (3*256 + tid) >> 4 };
    short8 qf[4];
#pragma unroll
    for (int hc = 0; hc < 4; ++hc)
        qf[hc] = *(const short8*)(Qb + ((size_t)b*DT + qw + c) * DH + hc*32 + g*8);

    f32x4 acc[8] = {};
    float m = -1e30f, l = 0.f;

    if (kt0 < kt1){
        // ---- prologue: stage first tile into buf 0 ----
        {
            const int kv0 = kt0 * 64;
#pragma unroll
            for (int p = 0; p < 4; ++p){
                const int s = p*256 + tid;
                const int r = s >> 4, cbl = (s & 15) * 16;
                const int h = s >> 3, tbl = (s & 7) * 16;
                gload16(Kbase + (size_t)(kv0 + r) * DH + ((cbl ^ ((r & 7) << 4)) >> 1),
                        lds[0] + s*16);
                gload16(Vbase + (size_t)h * DT + kv0 + ((tbl ^ ((h & 7) << 4)) >> 1),
                        lds[0] + 16384 + s*16);
            }
        }

        for (int kt = kt0; kt < kt1; ++kt){
            const int cur = (kt - kt0) & 1;
            const int kv0c = kt * 64;
            __syncthreads();                      // buf[cur] staged (vmcnt drained)

            // ---- issue next tile direct-to-LDS (buf[cur^1]) ----
            if (kt + 1 < kt1){
                const int nv0 = kv0c + 64;
#pragma unroll
                for (int p = 0; p < 4; ++p){
                    const int s = p*256 + tid;
                    const int r = s >> 4, cbl = (s & 15) * 16;
                    const int h = s >> 3, tbl = (s & 7) * 16;
                    gload16(Kbase + (size_t)(nv0 + r) * DH + ((cbl ^ ((r & 7) << 4)) >> 1),
                            lds[cur ^ 1] + s*16);
                    gload16(Vbase + (size_t)h * DT + nv0 + ((tbl ^ ((h & 7) << 4)) >> 1),
                            lds[cur ^ 1] + 16384 + s*16);
                }
            }

            const unsigned char* kb = lds[cur];
            const unsigned char* vb = lds[cur] + 16384;

            // ---- QK^T from LDS K ----
            f32x4 s4[4] = {};
            short8 kf[4][4];
#pragma unroll
            for (int j = 0; j < 4; ++j){
                const int r = 16*j + c;
#pragma unroll
                for (int hc = 0; hc < 4; ++hc)
                    kf[j][hc] = *(const short8*)(kb + r*256 + ((hc*64 + g*16) ^ ((r & 7) << 4)));
            }
            __builtin_amdgcn_s_setprio(1);
#pragma unroll
            for (int hc = 0; hc < 4; ++hc)
#pragma unroll
                for (int j = 0; j < 4; ++j)
                    s4[j] = __builtin_amdgcn_mfma_f32_16x16x32_bf16(kf[j][hc], qf[hc], s4[j], 0,0,0);
            __builtin_amdgcn_s_setprio(0);

            // ---- causal mask (diagonal tile only) ----
            if (kt == nt - 1){
#pragma unroll
                for (int j = 0; j < 4; ++j){
                    const int o = kv0c + 16*j + 4*g;
#pragma unroll
                    for (int r = 0; r < 4; ++r)
                        if (o + r > q) s4[j][r] = -1e30f;
                }
            }

            // ---- online softmax with defer-max (T13) ----
            float tm = -1e30f;
#pragma unroll
            for (int j = 0; j < 4; ++j)
#pragma unroll
                for (int r = 0; r < 4; ++r) tm = fmaxf(tm, s4[j][r]);
            tm = fmaxf(tm, __shfl_xor(tm, 16));
            tm = fmaxf(tm, __shfl_xor(tm, 32));
            if (!__all(tm <= m + 8.f)){
                const float mn = fmaxf(m, tm);
                const float rs = exp2f(m - mn);
                l *= rs;
#pragma unroll
                for (int mt = 0; mt < 8; ++mt) acc[mt] *= rs;
                m = mn;
            }
            float p[4][4]; float ps = 0.f;
#pragma unroll
            for (int j = 0; j < 4; ++j)
#pragma unroll
                for (int r = 0; r < 4; ++r){
                    p[j][r] = exp2f(s4[j][r] - m);
                    ps += p[j][r];
                }
            ps += __shfl_xor(ps, 16);
            ps += __shfl_xor(ps, 32);
            l += ps;

            // ---- P -> B-fragment layout ----
            short8 pf0 = redist(pbf2(p[0][0], p[0][1]), pbf2(p[0][2], p[0][3]),
                                pbf2(p[1][0], p[1][1]), pbf2(p[1][2], p[1][3]), g, c);
            short8 pf1 = redist(pbf2(p[2][0], p[2][1]), pbf2(p[2][2], p[2][3]),
                                pbf2(p[3][0], p[3][1]), pbf2(p[3][2], p[3][3]), g, c);

            // ---- PV from LDS V ----
#pragma unroll
            for (int kk = 0; kk < 2; ++kk){
                short8 vf[8];
#pragma unroll
                for (int mt = 0; mt < 8; ++mt){
                    const int h = mt*16 + c;
                    vf[mt] = *(const short8*)(vb + h*128 + ((kk*64 + g*16) ^ ((h & 7) << 4)));
                }
                const short8 pf = kk ? pf1 : pf0;
                __builtin_amdgcn_s_setprio(1);
#pragma unroll
                for (int mt = 0; mt < 8; ++mt)
                    acc[mt] = __builtin_amdgcn_mfma_f32_16x16x32_bf16(vf[mt], pf, acc[mt], 0,0,0);
                __builtin_amdgcn_s_setprio(0);
            }
        }
    }

    // ---- store partial (bf16 O, f32 m/l) ----
    const size_t blk = ((size_t)(b * 32 + qt) * 2 + half);
    unsigned short* op = OP + blk * 8192;          // [64][128]
    const int row = 16*w + c;
#pragma unroll
    for (int mt = 0; mt < 8; ++mt){
        u16x4 h = { bfbits(acc[mt][0]), bfbits(acc[mt][1]),
                    bfbits(acc[mt][2]), bfbits(acc[mt][3]) };
        *(u16x4*)(op + row*128 + mt*16 + 4*g) = h;
    }
    if (g == 0){
        ML[(blk*64 + row)*2    ] = m;
        ML[(blk*64 + row)*2 + 1] = l;
    }
}

// 2-way merge. Grid 256 = (b, qt), 256 threads: r = tid>>2, colgroup = tid&3.
__global__ __launch_bounds__(256) void merge_kernel(const unsigned short* __restrict__ OP,
                                                    const float* __restrict__ ML,
                                                    float* __restrict__ out){
    const int tid = threadIdx.x;
    const int r  = tid >> 2;
    const int cq = (tid & 3) * 32;
    const int bi = blockIdx.x;
    const int b  = bi & 7;
    const int qt = bi >> 3;
    const size_t blk = (size_t)(b * 32 + qt) * 2;

    float ms[2], ls[2];
#pragma unroll
    for (int s = 0; s < 2; ++s){
        ms[s] = ML[((blk + s)*64 + r)*2    ];
        ls[s] = ML[((blk + s)*64 + r)*2 + 1];
    }
    const float M = fmaxf(ms[0], ms[1]);
    float sc[2]; float L = 0.f;
#pragma unroll
    for (int s = 0; s < 2; ++s){ sc[s] = exp2f(ms[s] - M); L += ls[s] * sc[s]; }
    const float inv = 1.0f / L;

    float* orow = out + ((size_t)(b * DT + qt*64 + r)) * DH + cq;
#pragma unroll
    for (int j = 0; j < 4; ++j){
        float o[8] = {};
#pragma unroll
        for (int s = 0; s < 2; ++s){
            short8 v = *(const short8*)(OP + (blk + s)*8192 + r*128 + cq + j*8);
#pragma unroll
            for (int e = 0; e < 8; ++e)
                o[e] += bf2f((unsigned short)v[e]) * sc[s];
        }
        f32x4 o0 = { o[0]*inv, o[1]*inv, o[2]*inv, o[3]*inv };
        f32x4 o1 = { o[4]*inv, o[5]*inv, o[6]*inv, o[7]*inv };
        *(f32x4*)(orow + j*8    ) = o0;
        *(f32x4*)(orow + j*8 + 4) = o1;
    }
}

extern "C" void kernel_launch(void* const* d_in, const int* in_sizes, int n_in,
                              void* d_out, int out_size, void* d_ws, size_t ws_size,
                              hipStream_t stream){
    const float* x  = (const float*)d_in[0];
    const float* Wq = (const float*)d_in[1];
    const float* Wk = (const float*)d_in[2];
    const float* Wv = (const float*)d_in[3];
    float* out = (float*)d_out;

    unsigned short* WTc = (unsigned short*)d_ws;         // [32][4][384][8] bf16
    unsigned short* Qb = WTc + 3 * DH * DC;              // [B*T][H]
    unsigned short* Kb = Qb + (size_t)DB * DT * DH;      // [B*T][H]
    unsigned short* VT = Kb + (size_t)DB * DT * DH;      // [B][H][T]
    unsigned short* OP = VT + (size_t)DB * DT * DH;      // [512][64][128] bf16
    float*          ML = (float*)(OP + (size_t)512 * 8192);  // [512][64][2] f32

    hipLaunchKernelGGL(prep_wt_kernel, dim3(1536), dim3(256), 0, stream, Wq, Wk, Wv, WTc);
    hipLaunchKernelGGL(qkv_kernel, dim3(256), dim3(512), 0, stream, x, WTc, Qb, Kb, VT);
    hipLaunchKernelGGL(attn_kernel, dim3(512), dim3(256), 0, stream, Qb, Kb, VT, OP, ML);
    hipLaunchKernelGGL(merge_kernel, dim3(256), dim3(256), 0, stream, OP, ML, out);
}

// Round 14
// 74.224 us; speedup vs baseline: 1.6909x; 1.0545x over previous
//
#include <hip/hip_runtime.h>
#include <hip/hip_bf16.h>

#define DB 8
#define DT 2048
#define DC 1024
#define DH 128

typedef __attribute__((ext_vector_type(8))) short short8;
typedef __attribute__((ext_vector_type(4))) float f32x4;
typedef __attribute__((ext_vector_type(4))) int i32x4;
typedef __attribute__((ext_vector_type(4))) unsigned short u16x4;

// round-to-nearest-even f32 -> bf16 bits
static __device__ __forceinline__ unsigned short bfbits(float x){
    union { float f; unsigned u; } a; a.f = x;
    unsigned u = a.u;
    unsigned r = u + 0x7fffu + ((u >> 16) & 1u);
    return (unsigned short)(r >> 16);
}
static __device__ __forceinline__ unsigned pbf2(float lo, float hi){
    return (unsigned)bfbits(lo) | ((unsigned)bfbits(hi) << 16);
}
static __device__ __forceinline__ float bf2f(unsigned short u){
    union { unsigned u; float f; } t; t.u = ((unsigned)u) << 16; return t.f;
}

// async 16B global -> LDS (direct, no VGPR round-trip)
static __device__ __forceinline__ void gload16(const void* g, void* l){
    __builtin_amdgcn_global_load_lds(
        (const __attribute__((address_space(1))) unsigned int*)g,
        (__attribute__((address_space(3))) unsigned int*)l, 16, 0, 0);
}

// Redistribute 32 kv-wide P slice into PV B-fragment layout. Verified R0..R12.
static __device__ __forceinline__ short8 redist(unsigned pk0, unsigned pk1,
                                                unsigned pk2, unsigned pk3,
                                                int g, int c){
    const int src0 = c + (((2*g    ) & 3) << 4);
    const int src1 = c + (((2*g + 1) & 3) << 4);
    const int sel  = g >> 1;
    unsigned a0 = __shfl(pk0, src0), a2 = __shfl(pk2, src0);
    unsigned b0 = __shfl(pk1, src0), b2 = __shfl(pk3, src0);
    unsigned c0 = __shfl(pk0, src1), c2 = __shfl(pk2, src1);
    unsigned d0 = __shfl(pk1, src1), d2 = __shfl(pk3, src1);
    i32x4 pw = { (int)(sel ? a2 : a0), (int)(sel ? b2 : b0),
                 (int)(sel ? c2 : c0), (int)(sel ? d2 : d0) };
    return __builtin_bit_cast(short8, pw);
}

// WTc[t][chunk][n][e] = W_p[k][h] bf16 (unchanged).
__global__ __launch_bounds__(256) void prep_wt_kernel(const float* __restrict__ Wq,
                                                      const float* __restrict__ Wk,
                                                      const float* __restrict__ Wv,
                                                      unsigned short* __restrict__ WTc){
    int gid = blockIdx.x * 256 + threadIdx.x;
    int e  = gid & 7;
    int F3 = gid >> 3;
    int n  = F3 % 384;
    int ct = F3 / 384;
    int k  = (ct >> 2) * 32 + (ct & 3) * 8 + e;
    int p  = n >> 7, h = n & 127;
    const float* W = (p == 0) ? Wq : (p == 1 ? Wk : Wv);
    float v = W[(size_t)k * DH + h];
    if (p == 0) v *= 0.08838834764831845f * 1.4426950408889634f;
    WTc[gid] = bfbits(v);
}

// Fused QKV projection v5: BM=64, grid 256 (the R12-passing residency:
// 1 block/CU), but BK=64 -> 16 barriers instead of 32, 24 MFMA/wave/iter.
// B staged via global_load_lds (6x16B/thread, linear dest); A reg-staged
// (all 512 threads, stride-72 rows). One barrier per iteration.
__global__ __launch_bounds__(512, 2) void qkv_kernel(const float* __restrict__ x,
                                                     const unsigned short* __restrict__ WTc,
                                                     unsigned short* __restrict__ Qb,
                                                     unsigned short* __restrict__ Kb,
                                                     unsigned short* __restrict__ VT){
    __shared__ unsigned short Bs[2][24576];   // 2 x 48KB (BK=64: two 32-k chunks)
    __shared__ unsigned short As[2][4608];    // 2 x 9KB  (64 rows x stride 72)

    const int tid  = threadIdx.x;
    const int lane = tid & 63;
    const int w    = tid >> 6;
    const int g = lane >> 4, c = lane & 15;
    const int m0 = blockIdx.x * 64;
    const int n0 = w * 48;

    const unsigned short* bsrc = WTc + (size_t)tid * 8;   // + j*4096 + t*24576
    const int arow = tid >> 3, ac8 = tid & 7;             // 64 rows x 8 chunks
    const float* asrc = x + (size_t)(m0 + arow) * DC + ac8 * 8;

    f32x4 acc[4][3] = {};
    float4 av0, av1;

    // ---- prologue: stage tile 0 ----
#pragma unroll
    for (int j = 0; j < 6; ++j)
        gload16(bsrc + j * 4096, &Bs[0][j * 4096 + tid * 8]);
    {
        av0 = *(const float4*)asrc; av1 = *(const float4*)(asrc + 4);
        i32x4 h8 = { (int)pbf2(av0.x, av0.y), (int)pbf2(av0.z, av0.w),
                     (int)pbf2(av1.x, av1.y), (int)pbf2(av1.z, av1.w) };
        *(i32x4*)(&As[0][arow * 72 + ac8 * 8]) = h8;
    }

    for (int t = 0; t < DC / 64; ++t){
        const int cur = t & 1;
        __syncthreads();                 // buf[cur] staged (vmcnt drained)
        if (t < DC / 64 - 1){
            // issue next B tile direct-to-LDS; A loads to regs (T14)
#pragma unroll
            for (int j = 0; j < 6; ++j)
                gload16(bsrc + (t + 1) * 24576 + j * 4096,
                        &Bs[cur ^ 1][j * 4096 + tid * 8]);
            av0 = *(const float4*)(asrc + (t + 1) * 64);
            av1 = *(const float4*)(asrc + (t + 1) * 64 + 4);
        }
#pragma unroll
        for (int kk = 0; kk < 2; ++kk){
            short8 af[4], bfr[3];
#pragma unroll
            for (int mf = 0; mf < 4; ++mf)
                af[mf] = *(const short8*)(&As[cur][(mf*16 + c) * 72 + kk*32 + g * 8]);
#pragma unroll
            for (int nf = 0; nf < 3; ++nf)
                bfr[nf] = *(const short8*)(&Bs[cur][kk*12288 + g * 3072 + (n0 + nf*16 + c) * 8]);
#pragma unroll
            for (int mf = 0; mf < 4; ++mf)
#pragma unroll
                for (int nf = 0; nf < 3; ++nf)
                    acc[mf][nf] = __builtin_amdgcn_mfma_f32_16x16x32_bf16(af[mf], bfr[nf], acc[mf][nf], 0, 0, 0);
        }
        if (t < DC / 64 - 1){
            i32x4 h8 = { (int)pbf2(av0.x, av0.y), (int)pbf2(av0.z, av0.w),
                         (int)pbf2(av1.x, av1.y), (int)pbf2(av1.z, av1.w) };
            *(i32x4*)(&As[cur ^ 1][arow * 72 + ac8 * 8]) = h8;
        }
    }

    const int bb = m0 >> 11;
    const int tb = m0 & 2047;
#pragma unroll
    for (int mf = 0; mf < 4; ++mf)
#pragma unroll
        for (int nf = 0; nf < 3; ++nf){
            const int n  = n0 + nf*16;
            const int p  = n >> 7;
            const int np = (n & 127) + c;
            const int row = m0 + mf*16 + 4*g;
            if (p < 2){
                unsigned short* O = (p == 0) ? Qb : Kb;
#pragma unroll
                for (int r = 0; r < 4; ++r)
                    O[(size_t)(row + r) * DH + np] = bfbits(acc[mf][nf][r]);
            } else {
                const int t0 = tb + mf*16 + 4*g;
                u16x4 v = { bfbits(acc[mf][nf][0]), bfbits(acc[mf][nf][1]),
                            bfbits(acc[mf][nf][2]), bfbits(acc[mf][nf][3]) };
                *(u16x4*)(VT + ((size_t)bb * DH + np) * DT + t0) = v;
            }
        }
}

// Causal flash attention v7 (unchanged from R12 passing version).
__global__ __launch_bounds__(256, 2) void attn_kernel(const unsigned short* __restrict__ Qb,
                                                      const unsigned short* __restrict__ Kb,
                                                      const unsigned short* __restrict__ VT,
                                                      unsigned short* __restrict__ OP,
                                                      float* __restrict__ ML){
    __shared__ unsigned char lds[2][32768];   // per buf: K 16KB @0, V 16KB @16384

    const int tid  = threadIdx.x;
    const int lane = tid & 63;
    const int w    = tid >> 6;
    const int g = lane >> 4, c = lane & 15;
    const int bi = blockIdx.x;
    const int b  = bi & 7;
    const int idx = bi >> 3;               // 0..63
    const int qt   = (idx < 32) ? (31 - idx) : (idx - 32);
    const int half = idx >> 5;
    const int q0 = qt * 64;
    const int qw = q0 + 16 * w;
    const int q  = qw + c;
    const int nt = qt + 1;
    const int h1 = (nt + 1) >> 1;
    const int kt0 = half ? h1 : 0;
    const int kt1 = half ? nt : h1;

    const unsigned short* Kbase = Kb + (size_t)b * DT * DH;
    const unsigned short* Vbase = VT + (size_t)b * DH * DT;

    short8 qf[4];
#pragma unroll
    for (int hc = 0; hc < 4; ++hc)
        qf[hc] = *(const short8*)(Qb + ((size_t)b*DT + qw + c) * DH + hc*32 + g*8);

    f32x4 acc[8] = {};
    float m = -1e30f, l = 0.f;

    if (kt0 < kt1){
        // ---- prologue: stage first tile into buf 0 ----
        {
            const int kv0 = kt0 * 64;
#pragma unroll
            for (int p = 0; p < 4; ++p){
                const int s = p*256 + tid;
                const int r = s >> 4, cbl = (s & 15) * 16;
                const int h = s >> 3, tbl = (s & 7) * 16;
                gload16(Kbase + (size_t)(kv0 + r) * DH + ((cbl ^ ((r & 7) << 4)) >> 1),
                        lds[0] + s*16);
                gload16(Vbase + (size_t)h * DT + kv0 + ((tbl ^ ((h & 7) << 4)) >> 1),
                        lds[0] + 16384 + s*16);
            }
        }

        for (int kt = kt0; kt < kt1; ++kt){
            const int cur = (kt - kt0) & 1;
            const int kv0c = kt * 64;
            __syncthreads();                      // buf[cur] staged (vmcnt drained)

            // ---- issue next tile direct-to-LDS (buf[cur^1]) ----
            if (kt + 1 < kt1){
                const int nv0 = kv0c + 64;
#pragma unroll
                for (int p = 0; p < 4; ++p){
                    const int s = p*256 + tid;
                    const int r = s >> 4, cbl = (s & 15) * 16;
                    const int h = s >> 3, tbl = (s & 7) * 16;
                    gload16(Kbase + (size_t)(nv0 + r) * DH + ((cbl ^ ((r & 7) << 4)) >> 1),
                            lds[cur ^ 1] + s*16);
                    gload16(Vbase + (size_t)h * DT + nv0 + ((tbl ^ ((h & 7) << 4)) >> 1),
                            lds[cur ^ 1] + 16384 + s*16);
                }
            }

            const unsigned char* kb = lds[cur];
            const unsigned char* vb = lds[cur] + 16384;

            // ---- QK^T from LDS K ----
            f32x4 s4[4] = {};
            short8 kf[4][4];
#pragma unroll
            for (int j = 0; j < 4; ++j){
                const int r = 16*j + c;
#pragma unroll
                for (int hc = 0; hc < 4; ++hc)
                    kf[j][hc] = *(const short8*)(kb + r*256 + ((hc*64 + g*16) ^ ((r & 7) << 4)));
            }
            __builtin_amdgcn_s_setprio(1);
#pragma unroll
            for (int hc = 0; hc < 4; ++hc)
#pragma unroll
                for (int j = 0; j < 4; ++j)
                    s4[j] = __builtin_amdgcn_mfma_f32_16x16x32_bf16(kf[j][hc], qf[hc], s4[j], 0,0,0);
            __builtin_amdgcn_s_setprio(0);

            // ---- causal mask (diagonal tile only) ----
            if (kt == nt - 1){
#pragma unroll
                for (int j = 0; j < 4; ++j){
                    const int o = kv0c + 16*j + 4*g;
#pragma unroll
                    for (int r = 0; r < 4; ++r)
                        if (o + r > q) s4[j][r] = -1e30f;
                }
            }

            // ---- online softmax with defer-max (T13) ----
            float tm = -1e30f;
#pragma unroll
            for (int j = 0; j < 4; ++j)
#pragma unroll
                for (int r = 0; r < 4; ++r) tm = fmaxf(tm, s4[j][r]);
            tm = fmaxf(tm, __shfl_xor(tm, 16));
            tm = fmaxf(tm, __shfl_xor(tm, 32));
            if (!__all(tm <= m + 8.f)){
                const float mn = fmaxf(m, tm);
                const float rs = exp2f(m - mn);
                l *= rs;
#pragma unroll
                for (int mt = 0; mt < 8; ++mt) acc[mt] *= rs;
                m = mn;
            }
            float p[4][4]; float ps = 0.f;
#pragma unroll
            for (int j = 0; j < 4; ++j)
#pragma unroll
                for (int r = 0; r < 4; ++r){
                    p[j][r] = exp2f(s4[j][r] - m);
                    ps += p[j][r];
                }
            ps += __shfl_xor(ps, 16);
            ps += __shfl_xor(ps, 32);
            l += ps;

            // ---- P -> B-fragment layout ----
            short8 pf0 = redist(pbf2(p[0][0], p[0][1]), pbf2(p[0][2], p[0][3]),
                                pbf2(p[1][0], p[1][1]), pbf2(p[1][2], p[1][3]), g, c);
            short8 pf1 = redist(pbf2(p[2][0], p[2][1]), pbf2(p[2][2], p[2][3]),
                                pbf2(p[3][0], p[3][1]), pbf2(p[3][2], p[3][3]), g, c);

            // ---- PV from LDS V ----
#pragma unroll
            for (int kk = 0; kk < 2; ++kk){
                short8 vf[8];
#pragma unroll
                for (int mt = 0; mt < 8; ++mt){
                    const int h = mt*16 + c;
                    vf[mt] = *(const short8*)(vb + h*128 + ((kk*64 + g*16) ^ ((h & 7) << 4)));
                }
                const short8 pf = kk ? pf1 : pf0;
                __builtin_amdgcn_s_setprio(1);
#pragma unroll
                for (int mt = 0; mt < 8; ++mt)
                    acc[mt] = __builtin_amdgcn_mfma_f32_16x16x32_bf16(vf[mt], pf, acc[mt], 0,0,0);
                __builtin_amdgcn_s_setprio(0);
            }
        }
    }

    // ---- store partial (bf16 O, f32 m/l) ----
    const size_t blk = ((size_t)(b * 32 + qt) * 2 + half);
    unsigned short* op = OP + blk * 8192;          // [64][128]
    const int row = 16*w + c;
#pragma unroll
    for (int mt = 0; mt < 8; ++mt){
        u16x4 h = { bfbits(acc[mt][0]), bfbits(acc[mt][1]),
                    bfbits(acc[mt][2]), bfbits(acc[mt][3]) };
        *(u16x4*)(op + row*128 + mt*16 + 4*g) = h;
    }
    if (g == 0){
        ML[(blk*64 + row)*2    ] = m;
        ML[(blk*64 + row)*2 + 1] = l;
    }
}

// 2-way merge. Grid 256 = (b, qt), 256 threads: r = tid>>2, colgroup = tid&3.
__global__ __launch_bounds__(256) void merge_kernel(const unsigned short* __restrict__ OP,
                                                    const float* __restrict__ ML,
                                                    float* __restrict__ out){
    const int tid = threadIdx.x;
    const int r  = tid >> 2;
    const int cq = (tid & 3) * 32;
    const int bi = blockIdx.x;
    const int b  = bi & 7;
    const int qt = bi >> 3;
    const size_t blk = (size_t)(b * 32 + qt) * 2;

    float ms[2], ls[2];
#pragma unroll
    for (int s = 0; s < 2; ++s){
        ms[s] = ML[((blk + s)*64 + r)*2    ];
        ls[s] = ML[((blk + s)*64 + r)*2 + 1];
    }
    const float M = fmaxf(ms[0], ms[1]);
    float sc[2]; float L = 0.f;
#pragma unroll
    for (int s = 0; s < 2; ++s){ sc[s] = exp2f(ms[s] - M); L += ls[s] * sc[s]; }
    const float inv = 1.0f / L;

    float* orow = out + ((size_t)(b * DT + qt*64 + r)) * DH + cq;
#pragma unroll
    for (int j = 0; j < 4; ++j){
        float o[8] = {};
#pragma unroll
        for (int s = 0; s < 2; ++s){
            short8 v = *(const short8*)(OP + (blk + s)*8192 + r*128 + cq + j*8);
#pragma unroll
            for (int e = 0; e < 8; ++e)
                o[e] += bf2f((unsigned short)v[e]) * sc[s];
        }
        f32x4 o0 = { o[0]*inv, o[1]*inv, o[2]*inv, o[3]*inv };
        f32x4 o1 = { o[4]*inv, o[5]*inv, o[6]*inv, o[7]*inv };
        *(f32x4*)(orow + j*8    ) = o0;
        *(f32x4*)(orow + j*8 + 4) = o1;
    }
}

extern "C" void kernel_launch(void* const* d_in, const int* in_sizes, int n_in,
                              void* d_out, int out_size, void* d_ws, size_t ws_size,
                              hipStream_t stream){
    const float* x  = (const float*)d_in[0];
    const float* Wq = (const float*)d_in[1];
    const float* Wk = (const float*)d_in[2];
    const float* Wv = (const float*)d_in[3];
    float* out = (float*)d_out;

    unsigned short* WTc = (unsigned short*)d_ws;         // [32][4][384][8] bf16
    unsigned short* Qb = WTc + 3 * DH * DC;              // [B*T][H]
    unsigned short* Kb = Qb + (size_t)DB * DT * DH;      // [B*T][H]
    unsigned short* VT = Kb + (size_t)DB * DT * DH;      // [B][H][T]
    unsigned short* OP = VT + (size_t)DB * DT * DH;      // [512][64][128] bf16
    float*          ML = (float*)(OP + (size_t)512 * 8192);  // [512][64][2] f32

    hipLaunchKernelGGL(prep_wt_kernel, dim3(1536), dim3(256), 0, stream, Wq, Wk, Wv, WTc);
    hipLaunchKernelGGL(qkv_kernel, dim3(256), dim3(512), 0, stream, x, WTc, Qb, Kb, VT);
    hipLaunchKernelGGL(attn_kernel, dim3(512), dim3(256), 0, stream, Qb, Kb, VT, OP, ML);
    hipLaunchKernelGGL(merge_kernel, dim3(256), dim3(256), 0, stream, OP, ML, out);
}